// Round 1
// baseline (12369.737 us; speedup 1.0000x reference)
//
#include <hip/hip_runtime.h>

#define Bz 64
#define Sz 512
#define Iz 512
#define Hz 1024
#define Lz 6

typedef __attribute__((ext_vector_type(8))) short bf16x8;
typedef __attribute__((ext_vector_type(4))) float f32x4;

__device__ __forceinline__ unsigned short f2bf(float f) {
  unsigned u = __float_as_uint(f);
  u += 0x7fffu + ((u >> 16) & 1u);
  return (unsigned short)(u >> 16);
}

// add two packed bf16 pairs in f32, round-nearest-even back to packed bf16
__device__ __forceinline__ unsigned bfadd2(unsigned a, unsigned b) {
  float alo = __uint_as_float(a << 16);
  float ahi = __uint_as_float(a & 0xffff0000u);
  float blo = __uint_as_float(b << 16);
  float bhi = __uint_as_float(b & 0xffff0000u);
  float lo = alo + blo;
  float hi = ahi + bhi;
  unsigned ul = __float_as_uint(lo);
  ul += 0x7fffu + ((ul >> 16) & 1u);
  unsigned uh = __float_as_uint(hi);
  uh += 0x7fffu + ((uh >> 16) & 1u);
  return (ul >> 16) | (uh & 0xffff0000u);
}

__global__ void init_kernel(const float* __restrict__ wih, const float* __restrict__ bih,
                            const float* __restrict__ whh, const float* __restrict__ bhh,
                            const float* __restrict__ bout,
                            unsigned short* __restrict__ Wbf,
                            unsigned short* __restrict__ Wihbf,
                            unsigned short* __restrict__ hbuf,
                            float* __restrict__ bias0, float* __restrict__ bias1,
                            float* __restrict__ out) {
  int tid = blockIdx.x * blockDim.x + threadIdx.x;
  int nt = gridDim.x * blockDim.x;
  for (int i = tid; i < Hz * Hz; i += nt) Wbf[i] = f2bf(whh[i]);
  for (int i = tid; i < Hz * Iz; i += nt) Wihbf[i] = f2bf(wih[i]);
  for (int i = tid; i < 2 * Lz * Bz * Hz; i += nt) hbuf[i] = 0;
  for (int i = tid; i < Hz; i += nt) {
    bias0[i] = bih[i] + bhh[i];   // layer 0 bias
    bias1[i] = 2.0f * bhh[i];     // layers 1..5 bias (added twice in ref)
  }
  float b0 = bout[0];
  for (int i = tid; i < Bz * Sz; i += nt) out[i] = b0;
}

// One wavefront phase: for each layer l with valid t = w - l, compute
//   h_new[l] = tanh(A_l @ W^T + bias), A_l = h_prev[0] (l==0, plus x part via
//   extended K) or (a_{l-1} + h_prev[l]) (l>=1), all GEMMs bf16 MFMA, f32 accum.
// Grid: 6 layers x 16 N-tiles (64 cols each) = 96 WGs, 256 threads (4 waves).
// Wave tile: 64 rows (all batch) x 16 cols, full-K loop, BK=64.
__global__ __launch_bounds__(256) void phase_kernel(
    const float* __restrict__ x,
    const unsigned short* __restrict__ Wbf,
    const unsigned short* __restrict__ Wihbf,
    unsigned short* __restrict__ hbuf,
    const float* __restrict__ bias0, const float* __restrict__ bias1,
    const float* __restrict__ wout,
    float* __restrict__ dout, int w) {
  const int layer = blockIdx.x >> 4;
  const int ntile = blockIdx.x & 15;
  const int t = w - layer;
  if (t < 0 || t >= Sz) return;
  const int c0 = ntile * 64;

  __shared__ unsigned short Alds[64 * 64];  // [row 0..63][k 0..63], XOR-swizzled
  __shared__ unsigned short Wlds[64 * 64];  // [col 0..63][k 0..63], XOR-swizzled

  const int tid = threadIdx.x;
  const int lane = tid & 63;
  const int wav = tid >> 6;
  const int cc = lane & 15;   // MFMA col / A-row-in-tile
  const int gg = lane >> 4;   // k-group

  const unsigned short* hrd = hbuf + (size_t)(w & 1) * (Lz * Bz * Hz);
  unsigned short* hwr = hbuf + (size_t)((w + 1) & 1) * (Lz * Bz * Hz);

  const int nk = (layer == 0) ? (Hz + Iz) / 64 : Hz / 64;  // 24 or 16 K-steps

  f32x4 acc[4];
#pragma unroll
  for (int m = 0; m < 4; ++m) acc[m] = (f32x4){0.f, 0.f, 0.f, 0.f};

  // staging mapping: thread -> (row, 16-elem k-quarter)
  const int sr = tid >> 2;          // 0..63
  const int skq = (tid & 3) << 4;   // 0,16,32,48

  for (int step = 0; step < nk; ++step) {
    const int kk0 = step * 64;
    __syncthreads();
    // ---- stage A tile (activations, summed for l>=1), rows = batch
    {
#pragma unroll
      for (int cch = 0; cch < 2; ++cch) {
        const int kl = skq + cch * 8;
        const int kg = kk0 + kl;
        uint4 w16;
        if (layer > 0) {
          const uint4 v1 = *reinterpret_cast<const uint4*>(
              hrd + ((size_t)(layer - 1) * Bz + sr) * Hz + kg);
          const uint4 v2 = *reinterpret_cast<const uint4*>(
              hrd + ((size_t)layer * Bz + sr) * Hz + kg);
          w16.x = bfadd2(v1.x, v2.x);
          w16.y = bfadd2(v1.y, v2.y);
          w16.z = bfadd2(v1.z, v2.z);
          w16.w = bfadd2(v1.w, v2.w);
        } else if (kg < Hz) {
          w16 = *reinterpret_cast<const uint4*>(hrd + (size_t)sr * Hz + kg);
        } else {  // layer 0, x part of the extended K range
          const float* xs = x + ((size_t)sr * Sz + t) * Iz + (kg - Hz);
          float4 f0 = *reinterpret_cast<const float4*>(xs);
          float4 f1 = *reinterpret_cast<const float4*>(xs + 4);
          w16.x = (unsigned)f2bf(f0.x) | ((unsigned)f2bf(f0.y) << 16);
          w16.y = (unsigned)f2bf(f0.z) | ((unsigned)f2bf(f0.w) << 16);
          w16.z = (unsigned)f2bf(f1.x) | ((unsigned)f2bf(f1.y) << 16);
          w16.w = (unsigned)f2bf(f1.z) | ((unsigned)f2bf(f1.w) << 16);
        }
        const int idx = sr * 64 + (kl ^ ((sr & 7) << 3));
        *reinterpret_cast<uint4*>(&Alds[idx]) = w16;
      }
    }
    // ---- stage W tile (pre-converted bf16 weights), rows = output cols
    {
#pragma unroll
      for (int cch = 0; cch < 2; ++cch) {
        const int kl = skq + cch * 8;
        const int kg = kk0 + kl;
        const unsigned short* src =
            (kg < Hz) ? (Wbf + (size_t)(c0 + sr) * Hz + kg)
                      : (Wihbf + (size_t)(c0 + sr) * Iz + (kg - Hz));
        uint4 v = *reinterpret_cast<const uint4*>(src);
        const int idx = sr * 64 + (kl ^ ((sr & 7) << 3));
        *reinterpret_cast<uint4*>(&Wlds[idx]) = v;
      }
    }
    __syncthreads();
    // ---- compute: 2 k-subtiles of 32, 4 M-frags x 1 N-frag per wave
#pragma unroll
    for (int ks = 0; ks < 2; ++ks) {
      const int k8 = ks * 32 + gg * 8;
      const int wrow = wav * 16 + cc;
      const bf16x8 bfrag = *reinterpret_cast<const bf16x8*>(
          &Wlds[wrow * 64 + (k8 ^ ((wrow & 7) << 3))]);
#pragma unroll
      for (int m = 0; m < 4; ++m) {
        const int ra = m * 16 + cc;
        const bf16x8 afrag = *reinterpret_cast<const bf16x8*>(
            &Alds[ra * 64 + (k8 ^ ((ra & 7) << 3))]);
        acc[m] = __builtin_amdgcn_mfma_f32_16x16x32_bf16(afrag, bfrag, acc[m], 0, 0, 0);
      }
    }
  }

  // ---- epilogue: bias + tanh, write h (bf16), h_final (f32), out dot (atomic)
  const int col = c0 + wav * 16 + cc;
  const float bv = (layer == 0) ? bias0[col] : bias1[col];
  float hv[4][4];
#pragma unroll
  for (int m = 0; m < 4; ++m) {
#pragma unroll
    for (int i = 0; i < 4; ++i) {
      const int brow = m * 16 + gg * 4 + i;  // C/D row = (lane>>4)*4 + reg
      const float v = tanhf(acc[m][i] + bv);
      hv[m][i] = v;
      hwr[((size_t)layer * Bz + brow) * Hz + col] = f2bf(v);
      if (t == Sz - 1)
        dout[Bz * Sz + ((size_t)layer * Bz + brow) * Hz + col] = v;
    }
  }
  if (layer == Lz - 1) {
    const float wov = wout[col];
#pragma unroll
    for (int m = 0; m < 4; ++m) {
#pragma unroll
      for (int i = 0; i < 4; ++i) {
        float pv = hv[m][i] * wov;
        pv += __shfl_xor(pv, 1);
        pv += __shfl_xor(pv, 2);
        pv += __shfl_xor(pv, 4);
        pv += __shfl_xor(pv, 8);
        if (cc == 0) {
          const int brow = m * 16 + gg * 4 + i;
          atomicAdd(&dout[(size_t)brow * Sz + t], pv);
        }
      }
    }
  }
}

extern "C" void kernel_launch(void* const* d_in, const int* in_sizes, int n_in,
                              void* d_out, int out_size, void* d_ws, size_t ws_size,
                              hipStream_t stream) {
  (void)in_sizes; (void)n_in; (void)out_size; (void)ws_size;
  const float* x    = (const float*)d_in[0];
  const float* wih  = (const float*)d_in[1];
  const float* bih  = (const float*)d_in[2];
  const float* whh  = (const float*)d_in[3];
  const float* bhh  = (const float*)d_in[4];
  const float* wout = (const float*)d_in[5];
  const float* bout = (const float*)d_in[6];
  float* out = (float*)d_out;
  char* ws = (char*)d_ws;
  // ws layout: [0,2MB) W_hh bf16 | [2MB,3MB) W_ih bf16 | [3MB,4.5MB) h dbl-buf
  //            [4.5MB,+8KB) bias0/bias1
  unsigned short* Wbf   = (unsigned short*)(ws);
  unsigned short* Wihbf = (unsigned short*)(ws + ((size_t)2 << 20));
  unsigned short* hbuf  = (unsigned short*)(ws + ((size_t)3 << 20));
  float* bias0 = (float*)(ws + ((size_t)9 << 19));
  float* bias1 = bias0 + Hz;

  hipLaunchKernelGGL(init_kernel, dim3(1024), dim3(256), 0, stream,
                     wih, bih, whh, bhh, bout, Wbf, Wihbf, hbuf, bias0, bias1, out);
  for (int w = 0; w < Sz + Lz - 1; ++w) {
    hipLaunchKernelGGL(phase_kernel, dim3(96), dim3(256), 0, stream,
                       x, Wbf, Wihbf, hbuf, bias0, bias1, wout, out, w);
  }
}